// Round 12
// baseline (253.396 us; speedup 1.0000x reference)
//
#include <hip/hip_runtime.h>
#include <hip/hip_bf16.h>

// N=1024 rois, DF=1024, DK=DV=DG=64, NR=16 heads.
// ws: [0,32MB) w=max(relu(pe@Wg^T+bg),1e-6) f16 [16][1024][1024]
//     [32MB) Q bf16 [16][1024][64]; [34MB) K same; [36MB) Vt bf16 [16][64][1024]; [38MB) Y bf16 [1024][1024]

typedef __bf16 bf16_t;
typedef _Float16 f16_t;
typedef __attribute__((ext_vector_type(8))) __bf16 bf16x8;
typedef __attribute__((ext_vector_type(8))) _Float16 f16x8;
typedef __attribute__((ext_vector_type(2))) _Float16 f16x2;
typedef __attribute__((ext_vector_type(4))) float f32x4;
typedef __attribute__((ext_vector_type(2))) float f32x2;

__device__ inline bf16_t f2b(float f) {
    unsigned u = __builtin_bit_cast(unsigned, f);
    unsigned r = u + 0x7fffu + ((u >> 16) & 1u);
    unsigned short h = (unsigned short)(r >> 16);
    return __builtin_bit_cast(bf16_t, h);
}

// ---- fused (g + Q/K/V projections) heterogeneous kernel ----
// blocks [0,4096): g. blocks [4096,4096+768): proj z=(bid-4096)/256.
// g design (R8-R10 counter synthesis): quarter-row lanes (64B segments),
// 2-chunk reg prefetch (4KB/wave in flight), NO barriers (wave-private LDS
// out-tile only), packed f32x2 FMAs, full-line f16 stores, f32 math.
__global__ __launch_bounds__(256, 6) void fused_g_proj_k(
        const float* __restrict__ pe, const float* __restrict__ Wg, const float* __restrict__ bg,
        f16_t* __restrict__ Wout,
        const float* __restrict__ x,
        const float* __restrict__ Wq, const float* __restrict__ bq, bf16_t* __restrict__ Qb,
        const float* __restrict__ Wk, const float* __restrict__ bk, bf16_t* __restrict__ Kb,
        const float* __restrict__ Wv, const float* __restrict__ bv, bf16_t* __restrict__ Vb) {
    __shared__ char smem_raw[20480];       // proj: As|Bs (2x10240). g: 4 x [64][18] f16 (9216).
    const int bid = blockIdx.x;
    const int t = threadIdx.x;

    if (bid < 4096) {
        // ================= g: w = max(relu(pe@Wg^T+bg), 1e-6) =================
        // f32 math (precision cliff at relu boundary — round-2 lesson).
        const int w = t >> 6, lane = t & 63;
        const int r = lane >> 2, c = lane & 3;
        const long g0 = ((long)bid * 4 + w) * 64;          // this wave's 64-row group
        f16_t* gout = (f16_t*)smem_raw + w * (64 * 18);    // wave-private out tile

        const float* pebase = pe + (g0 << 6);
        // chunk s: rows [s*16, s*16+16); lane covers floats [c*16, c*16+16)... split
        // as 4 x float4 at +0,+16,+32,+48 so each instr is a 64B segment x 16 rows.
        float4 pc0, pc1, pc2, pc3, pn0, pn1, pn2, pn3;
        {
            const float* p0 = pebase + (r << 6) + (c << 2);
            pc0 = *(const float4*)(p0);
            pc1 = *(const float4*)(p0 + 16);
            pc2 = *(const float4*)(p0 + 32);
            pc3 = *(const float4*)(p0 + 48);
        }
        unsigned cof = c << 2;                 // float offset of lane's sub-quarter
        for (int s = 0; s < 4; s++) {
            if (s < 3) {  // prefetch next chunk (T14 issue-early)
                const float* p1 = pebase + (((s + 1) * 16 + r) << 6) + (c << 2);
                pn0 = *(const float4*)(p1);
                pn1 = *(const float4*)(p1 + 16);
                pn2 = *(const float4*)(p1 + 32);
                pn3 = *(const float4*)(p1 + 48);
            }
            asm volatile("" : "+v"(cof));      // block LICM: Wg loads stay per-chunk
            float p[16];
#pragma unroll
            for (int h = 0; h < 16; h++) {
                const float* wgh = Wg + (h << 6) + cof;
                float4 w0 = *(const float4*)(wgh);
                float4 w1 = *(const float4*)(wgh + 16);
                float4 w2 = *(const float4*)(wgh + 32);
                float4 w3 = *(const float4*)(wgh + 48);
                f32x2 a = {0.f, 0.f};
                a = __builtin_elementwise_fma((f32x2){pc0.x, pc0.y}, (f32x2){w0.x, w0.y}, a);
                a = __builtin_elementwise_fma((f32x2){pc0.z, pc0.w}, (f32x2){w0.z, w0.w}, a);
                a = __builtin_elementwise_fma((f32x2){pc1.x, pc1.y}, (f32x2){w1.x, w1.y}, a);
                a = __builtin_elementwise_fma((f32x2){pc1.z, pc1.w}, (f32x2){w1.z, w1.w}, a);
                a = __builtin_elementwise_fma((f32x2){pc2.x, pc2.y}, (f32x2){w2.x, w2.y}, a);
                a = __builtin_elementwise_fma((f32x2){pc2.z, pc2.w}, (f32x2){w2.z, w2.w}, a);
                a = __builtin_elementwise_fma((f32x2){pc3.x, pc3.y}, (f32x2){w3.x, w3.y}, a);
                a = __builtin_elementwise_fma((f32x2){pc3.z, pc3.w}, (f32x2){w3.z, w3.w}, a);
                p[h] = a.x + a.y;
            }
#pragma unroll
            for (int h = 0; h < 16; h++) {     // 4-lane butterfly + bias + clamp
                p[h] += __shfl_xor(p[h], 1);
                p[h] += __shfl_xor(p[h], 2);
                // w = max(relu(p+bg),1e-6) == max(p+bg,1e-6); softmax(qk+log w)==w*e^qk/sum
                p[h] = fmaxf(p[h] + bg[h], 1e-6f);
            }
            // lane stores heads [c*4, c*4+4) for its row — static select (rule 20)
            float s0 = (c & 2) ? ((c & 1) ? p[12] : p[8]) : ((c & 1) ? p[4] : p[0]);
            float s1 = (c & 2) ? ((c & 1) ? p[13] : p[9]) : ((c & 1) ? p[5] : p[1]);
            float s2 = (c & 2) ? ((c & 1) ? p[14] : p[10]) : ((c & 1) ? p[6] : p[2]);
            float s3 = (c & 2) ? ((c & 1) ? p[15] : p[11]) : ((c & 1) ? p[7] : p[3]);
            const int ob = (s * 16 + r) * 18 + (c << 2);
            *(f16x2*)&gout[ob]     = (f16x2){(f16_t)s0, (f16_t)s1};
            *(f16x2*)&gout[ob + 2] = (f16x2){(f16_t)s2, (f16_t)s3};
            if (s < 3) { pc0 = pn0; pc1 = pn1; pc2 = pn2; pc3 = pn3; }
        }
        // wave-sync store phase: per head, 64 rows = 128B full line (R9 lesson)
#pragma unroll
        for (int h = 0; h < 16; h++) {
            f16_t v = gout[lane * 18 + h];
            Wout[((long)h << 20) + g0 + lane] = v;
        }
    } else {
        // ================= projection GEMM: C = x @ W^T + b =================
        bf16_t (*As)[64][40] = (bf16_t(*)[64][40])smem_raw;            // [2][64][40]
        bf16_t (*Bs)[64][40] = (bf16_t(*)[64][40])(smem_raw + 10240);  // [2][64][40]
        const int rem = bid - 4096;
        const int z = rem >> 8, rem2 = rem & 255;
        const float* B = (z == 0) ? Wq : (z == 1) ? Wk : Wv;
        const float* bias = (z == 0) ? bq : (z == 1) ? bk : bv;
        bf16_t* outp = (z == 0) ? Qb : (z == 1) ? Kb : Vb;
        const int m0 = (rem2 >> 4) * 64, n0 = (rem2 & 15) * 64;
        const int lr = t >> 2, lq = t & 3;

        auto stage = [&](bf16_t (*dst)[64][40], const float* __restrict__ Sp, int row0, int buf, int k0) {
            const float* p = Sp + (long)(row0 + lr) * 1024 + k0 + lq * 8;
            float4 u0 = *(const float4*)p;
            float4 u1 = *(const float4*)(p + 4);
            bf16x8 v;
            v[0] = f2b(u0.x); v[1] = f2b(u0.y); v[2] = f2b(u0.z); v[3] = f2b(u0.w);
            v[4] = f2b(u1.x); v[5] = f2b(u1.y); v[6] = f2b(u1.z); v[7] = f2b(u1.w);
            *(bf16x8*)&dst[buf][lr][lq * 8] = v;
        };

        const int wid = t >> 6, lane = t & 63;
        const int wm = (wid >> 1) * 32, wn = (wid & 1) * 32;
        const int ml = lane & 15, kl = (lane >> 4) * 8;
        f32x4 acc[2][2] = {};

        stage(As, x, m0, 0, 0);
        stage(Bs, B, n0, 0, 0);
        __syncthreads();
        for (int kt = 0; kt < 32; kt++) {
            const int buf = kt & 1;
            if (kt + 1 < 32) { stage(As, x, m0, buf ^ 1, (kt + 1) * 32); stage(Bs, B, n0, buf ^ 1, (kt + 1) * 32); }
            bf16x8 a0 = *(const bf16x8*)&As[buf][wm + ml][kl];
            bf16x8 a1 = *(const bf16x8*)&As[buf][wm + 16 + ml][kl];
            bf16x8 b0 = *(const bf16x8*)&Bs[buf][wn + ml][kl];
            bf16x8 b1 = *(const bf16x8*)&Bs[buf][wn + 16 + ml][kl];
            acc[0][0] = __builtin_amdgcn_mfma_f32_16x16x32_bf16(a0, b0, acc[0][0], 0, 0, 0);
            acc[0][1] = __builtin_amdgcn_mfma_f32_16x16x32_bf16(a0, b1, acc[0][1], 0, 0, 0);
            acc[1][0] = __builtin_amdgcn_mfma_f32_16x16x32_bf16(a1, b0, acc[1][0], 0, 0, 0);
            acc[1][1] = __builtin_amdgcn_mfma_f32_16x16x32_bf16(a1, b1, acc[1][1], 0, 0, 0);
            __syncthreads();
        }

#pragma unroll
        for (int mt = 0; mt < 2; mt++)
#pragma unroll
            for (int nt = 0; nt < 2; nt++) {
                f32x4 v = acc[mt][nt];
                const int rbase = m0 + wm + mt * 16 + ((lane >> 4) << 2);
                const int col = n0 + wn + nt * 16 + (lane & 15);
#pragma unroll
                for (int r = 0; r < 4; r++) {
                    const int row = rbase + r;
                    float val = v[r] + bias[col];
                    int h = col >> 6, d = col & 63;
                    if (z < 2) outp[((long)h << 16) + ((long)row << 6) + d] = f2b(val);
                    else       outp[((long)h << 16) + ((long)d << 10) + row] = f2b(val);
                }
            }
    }
}

// ---- final GEMM: out f32 = Yb @ Wy^T + by + x ----
__global__ __launch_bounds__(256) void gemmY_k(const bf16_t* __restrict__ A,
                                               const float* __restrict__ Bw,
                                               const float* __restrict__ bias,
                                               float* __restrict__ outp,
                                               const float* __restrict__ extra) {
    __shared__ bf16_t As[2][64][40];
    __shared__ bf16_t Bs[2][64][40];
    const int t = threadIdx.x;
    const int m0 = blockIdx.y * 64, n0 = blockIdx.x * 64;
    const int lr = t >> 2, lq = t & 3;

    auto stageA = [&](int buf, int k0) {
        const bf16_t* p = A + (long)(m0 + lr) * 1024 + k0 + lq * 8;
        *(bf16x8*)&As[buf][lr][lq * 8] = *(const bf16x8*)p;
    };
    auto stageB = [&](int buf, int k0) {
        const float* p = Bw + (long)(n0 + lr) * 1024 + k0 + lq * 8;
        float4 u0 = *(const float4*)p;
        float4 u1 = *(const float4*)(p + 4);
        bf16x8 v;
        v[0] = f2b(u0.x); v[1] = f2b(u0.y); v[2] = f2b(u0.z); v[3] = f2b(u0.w);
        v[4] = f2b(u1.x); v[5] = f2b(u1.y); v[6] = f2b(u1.z); v[7] = f2b(u1.w);
        *(bf16x8*)&Bs[buf][lr][lq * 8] = v;
    };

    const int wid = t >> 6, lane = t & 63;
    const int wm = (wid >> 1) * 32, wn = (wid & 1) * 32;
    const int ml = lane & 15, kl = (lane >> 4) * 8;
    f32x4 acc[2][2] = {};

    stageA(0, 0);
    stageB(0, 0);
    __syncthreads();
    for (int kt = 0; kt < 32; kt++) {
        const int buf = kt & 1;
        if (kt + 1 < 32) { stageA(buf ^ 1, (kt + 1) * 32); stageB(buf ^ 1, (kt + 1) * 32); }
        bf16x8 a0 = *(const bf16x8*)&As[buf][wm + ml][kl];
        bf16x8 a1 = *(const bf16x8*)&As[buf][wm + 16 + ml][kl];
        bf16x8 b0 = *(const bf16x8*)&Bs[buf][wn + ml][kl];
        bf16x8 b1 = *(const bf16x8*)&Bs[buf][wn + 16 + ml][kl];
        acc[0][0] = __builtin_amdgcn_mfma_f32_16x16x32_bf16(a0, b0, acc[0][0], 0, 0, 0);
        acc[0][1] = __builtin_amdgcn_mfma_f32_16x16x32_bf16(a0, b1, acc[0][1], 0, 0, 0);
        acc[1][0] = __builtin_amdgcn_mfma_f32_16x16x32_bf16(a1, b0, acc[1][0], 0, 0, 0);
        acc[1][1] = __builtin_amdgcn_mfma_f32_16x16x32_bf16(a1, b1, acc[1][1], 0, 0, 0);
        __syncthreads();
    }

#pragma unroll
    for (int mt = 0; mt < 2; mt++)
#pragma unroll
        for (int nt = 0; nt < 2; nt++) {
            f32x4 v = acc[mt][nt];
            const int rbase = m0 + wm + mt * 16 + ((lane >> 4) << 2);
            const int col = n0 + wn + nt * 16 + (lane & 15);
#pragma unroll
            for (int r = 0; r < 4; r++) {
                const int row = rbase + r;
                long idx = ((long)row << 10) + col;
                outp[idx] = v[r] + bias[col] + extra[idx];
            }
        }
}

// ---- fused attention: per (qtile64, head): S=QK^T, p=exp(S)*w, O=pV, O/=sum ----
__global__ __launch_bounds__(256) void attn_kernel(const bf16_t* __restrict__ Q,
                                                   const bf16_t* __restrict__ K,
                                                   const bf16_t* __restrict__ Vt,
                                                   const f16_t* __restrict__ Wf,
                                                   bf16_t* __restrict__ Y) {
    __shared__ bf16_t Qs[64][72];
    __shared__ bf16_t Ks[2][64][72];
    __shared__ bf16_t Vts[2][64][72];
    __shared__ f16_t  Ws[2][64][72];
    __shared__ bf16_t Ps[4][16][72];

    const int qt = blockIdx.x, h = blockIdx.y;
    const int t = threadIdx.x;
    const int w = t >> 6, lane = t & 63;
    const int ml = lane & 15, kq = lane >> 4;
    const int q0 = qt << 6;
    const int sr = t >> 2, sc = (t & 3) << 4;

    const bf16_t* Kh = K + ((long)h << 16);
    const bf16_t* Vh = Vt + ((long)h << 16);
    const f16_t*  Wh = Wf + ((long)h << 20) + ((long)(q0 + sr) << 10);

    {   // stage Q + tile 0
        const bf16_t* src = Q + ((long)h << 16) + ((long)(q0 + sr) << 6) + sc;
        *(bf16x8*)&Qs[sr][sc]     = *(const bf16x8*)src;
        *(bf16x8*)&Qs[sr][sc + 8] = *(const bf16x8*)(src + 8);
        const bf16_t* ks = Kh + ((long)sr << 6) + sc;
        *(bf16x8*)&Ks[0][sr][sc]     = *(const bf16x8*)ks;
        *(bf16x8*)&Ks[0][sr][sc + 8] = *(const bf16x8*)(ks + 8);
        const bf16_t* vs = Vh + ((long)sr << 10) + sc;
        *(bf16x8*)&Vts[0][sr][sc]     = *(const bf16x8*)vs;
        *(bf16x8*)&Vts[0][sr][sc + 8] = *(const bf16x8*)(vs + 8);
        const f16_t* gs = Wh + sc;
        *(f16x8*)&Ws[0][sr][sc]     = *(const f16x8*)gs;
        *(f16x8*)&Ws[0][sr][sc + 8] = *(const f16x8*)(gs + 8);
    }
    __syncthreads();

    const bf16x8 aq0 = *(const bf16x8*)&Qs[(w << 4) + ml][kq * 8];
    const bf16x8 aq1 = *(const bf16x8*)&Qs[(w << 4) + ml][32 + kq * 8];

    f32x4 O[4] = {};
    float lsum[4] = {0.f, 0.f, 0.f, 0.f};

    int buf = 0;
    for (int kt = 0; kt < 16; kt++) {
        bf16x8 rk0, rk1, rv0, rv1;
        f16x8 rw0, rw1;
        const bool pf = (kt < 15);
        if (pf) {  // issue next-tile loads early (T14): latency hides under compute
            const int k0 = (kt + 1) << 6;
            const bf16_t* ks = Kh + ((long)(k0 + sr) << 6) + sc;
            rk0 = *(const bf16x8*)ks; rk1 = *(const bf16x8*)(ks + 8);
            const bf16_t* vs = Vh + ((long)sr << 10) + k0 + sc;
            rv0 = *(const bf16x8*)vs; rv1 = *(const bf16x8*)(vs + 8);
            const f16_t* gs = Wh + k0 + sc;
            rw0 = *(const f16x8*)gs; rw1 = *(const f16x8*)(gs + 8);
        }

        // QK^T: wave tile = 16 q-rows x 64 keys
        f32x4 s[4] = {};
#pragma unroll
        for (int c = 0; c < 4; c++) {
            bf16x8 bk0 = *(const bf16x8*)&Ks[buf][(c << 4) + ml][kq * 8];
            bf16x8 bk1 = *(const bf16x8*)&Ks[buf][(c << 4) + ml][32 + kq * 8];
            s[c] = __builtin_amdgcn_mfma_f32_16x16x32_bf16(aq0, bk0, s[c], 0, 0, 0);
            s[c] = __builtin_amdgcn_mfma_f32_16x16x32_bf16(aq1, bk1, s[c], 0, 0, 0);
        }
        // p = exp(s) * w   (softmax(qk+log w) == w*e^qk/sum; no max needed: |s|<~50)
#pragma unroll
        for (int c = 0; c < 4; c++) {
#pragma unroll
            for (int r = 0; r < 4; r++) {
                float wv = (float)Ws[buf][(w << 4) + (kq << 2) + r][(c << 4) + ml];
                float p = __expf(s[c][r]) * wv;
                lsum[r] += p;
                Ps[w][(kq << 2) + r][(c << 4) + ml] = f2b(p);
            }
        }
        // PV: A = P (per-wave LDS transpose), B = Vt rows (dv)
        const bf16x8 pa0 = *(const bf16x8*)&Ps[w][ml][kq * 8];
        const bf16x8 pa1 = *(const bf16x8*)&Ps[w][ml][32 + kq * 8];
#pragma unroll
        for (int c = 0; c < 4; c++) {
            bf16x8 v0 = *(const bf16x8*)&Vts[buf][(c << 4) + ml][kq * 8];
            bf16x8 v1 = *(const bf16x8*)&Vts[buf][(c << 4) + ml][32 + kq * 8];
            O[c] = __builtin_amdgcn_mfma_f32_16x16x32_bf16(pa0, v0, O[c], 0, 0, 0);
            O[c] = __builtin_amdgcn_mfma_f32_16x16x32_bf16(pa1, v1, O[c], 0, 0, 0);
        }

        if (pf) {  // write-late staging into the other buffer
            const int nb = buf ^ 1;
            *(bf16x8*)&Ks[nb][sr][sc]      = rk0;
            *(bf16x8*)&Ks[nb][sr][sc + 8]  = rk1;
            *(bf16x8*)&Vts[nb][sr][sc]     = rv0;
            *(bf16x8*)&Vts[nb][sr][sc + 8] = rv1;
            *(f16x8*)&Ws[nb][sr][sc]       = rw0;
            *(f16x8*)&Ws[nb][sr][sc + 8]   = rw1;
        }
        __syncthreads();
        buf ^= 1;
    }

#pragma unroll
    for (int r = 0; r < 4; r++) {
        float v = lsum[r];
        v += __shfl_xor(v, 1); v += __shfl_xor(v, 2);
        v += __shfl_xor(v, 4); v += __shfl_xor(v, 8);
        lsum[r] = 1.0f / v;
    }
    const int rowb = q0 + (w << 4) + (kq << 2);
    const int colb = (h << 6) + ml;
#pragma unroll
    for (int c = 0; c < 4; c++)
#pragma unroll
        for (int r = 0; r < 4; r++)
            Y[((long)(rowb + r) << 10) + colb + (c << 4)] = f2b(O[c][r] * lsum[r]);
}

extern "C" void kernel_launch(void* const* d_in, const int* in_sizes, int n_in,
                              void* d_out, int out_size, void* d_ws, size_t ws_size,
                              hipStream_t stream) {
    const float* x  = (const float*)d_in[0];
    const float* pe = (const float*)d_in[1];
    const float* Wq = (const float*)d_in[2];
    const float* bq = (const float*)d_in[3];
    const float* Wk = (const float*)d_in[4];
    const float* bk = (const float*)d_in[5];
    const float* Wv = (const float*)d_in[6];
    const float* bv = (const float*)d_in[7];
    const float* Wg = (const float*)d_in[8];
    const float* bg = (const float*)d_in[9];
    const float* Wy = (const float*)d_in[10];
    const float* by = (const float*)d_in[11];

    char* ws = (char*)d_ws;
    f16_t*  Wf = (f16_t*)ws;                         // 32 MB
    bf16_t* Qb = (bf16_t*)(ws + (32ul << 20));       // 2 MB
    bf16_t* Kb = (bf16_t*)(ws + (34ul << 20));       // 2 MB
    bf16_t* Vb = (bf16_t*)(ws + (36ul << 20));       // 2 MB
    bf16_t* Yb = (bf16_t*)(ws + (38ul << 20));       // 2 MB

    fused_g_proj_k<<<4096 + 768, 256, 0, stream>>>(pe, Wg, bg, Wf,
                                                   x, Wq, bq, Qb, Wk, bk, Kb, Wv, bv, Vb);
    attn_kernel<<<dim3(16, 16), 256, 0, stream>>>(Qb, Kb, Vb, Wf, Yb);
    gemmY_k<<<dim3(16, 16), 256, 0, stream>>>(Yb, Wy, by, (float*)d_out, x);
}

// Round 13
// 228.566 us; speedup vs baseline: 1.1086x; 1.1086x over previous
//
#include <hip/hip_runtime.h>
#include <hip/hip_bf16.h>

// N=1024 rois, DF=1024, DK=DV=DG=64, NR=16 heads.
// ws: [0,32MB) w=max(relu(pe@Wg^T+bg),1e-6) f16 [16][1024][1024]
//     [32MB) Q bf16 [16][1024][64]; [34MB) K same; [36MB) Vt bf16 [16][64][1024]; [38MB) Y bf16 [1024][1024]

typedef __bf16 bf16_t;
typedef _Float16 f16_t;
typedef __attribute__((ext_vector_type(8))) __bf16 bf16x8;
typedef __attribute__((ext_vector_type(8))) _Float16 f16x8;
typedef __attribute__((ext_vector_type(4))) float f32x4;

__device__ inline bf16_t f2b(float f) {
    unsigned u = __builtin_bit_cast(unsigned, f);
    unsigned r = u + 0x7fffu + ((u >> 16) & 1u);
    unsigned short h = (unsigned short)(r >> 16);
    return __builtin_bit_cast(bf16_t, h);
}

// ---- fused (g + Q/K/V projections) heterogeneous kernel ----
// blocks [0,4096): g — R5/R7 proven structure + global_load_lds async staging
//   (T3/T4): 4 chunks x 64 rows, 2 LDS buffers, counted vmcnt (never 0
//   mid-loop), raw s_barrier. Pre-swizzled GLOBAL addrs + linear LDS (rule 21);
//   XOR on read -> conflict-free 16-lane phases. f32 math (round-2 cliff).
// blocks [4096,4864): proj z=(bid-4096)/256 (R12-proven body).
__global__ __launch_bounds__(256) void fused_g_proj_k(
        const float* __restrict__ pe, const float* __restrict__ Wg, const float* __restrict__ bg,
        f16_t* __restrict__ Wout,
        const float* __restrict__ x,
        const float* __restrict__ Wq, const float* __restrict__ bq, bf16_t* __restrict__ Qb,
        const float* __restrict__ Wk, const float* __restrict__ bk, bf16_t* __restrict__ Kb,
        const float* __restrict__ Wv, const float* __restrict__ bv, bf16_t* __restrict__ Vb) {
    __shared__ char smem_raw[32768];   // g: 2 x [64][16] float4 (32KB). proj: As|Bs (20KB).
    const int bid = blockIdx.x;
    const int t = threadIdx.x;

    if (bid < 4096) {
        // ================= g: w = max(relu(pe@Wg^T+bg), 1e-6) =================
        const long ch0 = (long)bid * 4;            // 4 chunks of 64 rows
        const int w = t >> 6, lane = t & 63;
        const int r = lane;                        // compute row = lane
        const int hq = w << 2;                     // head quad per wave
        float4* tile = (float4*)smem_raw;          // [2][1024] float4, linear

        auto stageg = [&](int buf, long ch) {
            // LDS slot fi=(p*256+t) holds pe_row[cp^(rr&15)] -> read with same XOR.
#pragma unroll
            for (int p = 0; p < 4; p++) {
                int fi = p * 256 + t;
                int rr = fi >> 4, cp = fi & 15, cc = cp ^ (rr & 15);
                const float* gsrc = pe + (ch << 12) + (rr << 6) + (cc << 2);   // per-lane
                float4* ldst = tile + buf * 1024 + p * 256 + (w << 6);         // wave-uniform
                __builtin_amdgcn_global_load_lds((__attribute__((address_space(1))) const void*)gsrc,
                                                 (__attribute__((address_space(3))) void*)ldst, 16, 0, 0);
            }
        };

        stageg(0, ch0);
        for (int i = 0; i < 4; i++) {
            if (i < 3) stageg((i + 1) & 1, ch0 + i + 1);
            // counted vmcnt: oldest 4 loads (this chunk) must land; keep rest in flight.
            // outstanding order: [L_i 4][S_{i-1} 4][L_{i+1} 4] -> mid waits vmcnt(8).
            if (i == 0)      asm volatile("s_waitcnt vmcnt(4)" ::: "memory");
            else if (i < 3)  asm volatile("s_waitcnt vmcnt(8)" ::: "memory");
            else             asm volatile("s_waitcnt vmcnt(4)" ::: "memory");
            __builtin_amdgcn_s_barrier();          // raw: no vmcnt(0) drain
            __builtin_amdgcn_sched_barrier(0);
            const float4* tb = tile + (i & 1) * 1024 + (r << 4);
            float a0 = 0.f, a1 = 0.f, a2 = 0.f, a3 = 0.f;
#pragma unroll
            for (int half = 0; half < 2; half++) {
                float4 pv[8];
#pragma unroll
                for (int j = 0; j < 8; j++) {
                    int c = half * 8 + j;
                    pv[j] = tb[c ^ (r & 15)];
                }
                const float* wg0 = Wg + ((hq + 0) << 6) + (half << 5);  // wave-uniform -> s_load
                const float* wg1 = Wg + ((hq + 1) << 6) + (half << 5);
                const float* wg2 = Wg + ((hq + 2) << 6) + (half << 5);
                const float* wg3 = Wg + ((hq + 3) << 6) + (half << 5);
#pragma unroll
                for (int j = 0; j < 8; j++) {
                    float4 w0 = *(const float4*)(wg0 + j * 4);
                    float4 w1 = *(const float4*)(wg1 + j * 4);
                    float4 w2 = *(const float4*)(wg2 + j * 4);
                    float4 w3 = *(const float4*)(wg3 + j * 4);
                    a0 += pv[j].x * w0.x + pv[j].y * w0.y + pv[j].z * w0.z + pv[j].w * w0.w;
                    a1 += pv[j].x * w1.x + pv[j].y * w1.y + pv[j].z * w1.z + pv[j].w * w1.w;
                    a2 += pv[j].x * w2.x + pv[j].y * w2.y + pv[j].z * w2.z + pv[j].w * w2.w;
                    a3 += pv[j].x * w3.x + pv[j].y * w3.y + pv[j].z * w3.z + pv[j].w * w3.w;
                }
            }
            // w = max(relu(a+bg),1e-6) == max(a+bg,1e-6); softmax(qk+log w)==w*e^qk/sum
            const long rowg = ((ch0 + i) << 6) + r;   // 64 lanes -> 128B line per head
            Wout[((long)(hq + 0) << 20) + rowg] = (f16_t)fmaxf(a0 + bg[hq + 0], 1e-6f);
            Wout[((long)(hq + 1) << 20) + rowg] = (f16_t)fmaxf(a1 + bg[hq + 1], 1e-6f);
            Wout[((long)(hq + 2) << 20) + rowg] = (f16_t)fmaxf(a2 + bg[hq + 2], 1e-6f);
            Wout[((long)(hq + 3) << 20) + rowg] = (f16_t)fmaxf(a3 + bg[hq + 3], 1e-6f);
            __builtin_amdgcn_s_barrier();          // all reads done before restage
        }
    } else {
        // ================= projection GEMM: C = x @ W^T + b =================
        bf16_t (*As)[64][40] = (bf16_t(*)[64][40])smem_raw;            // [2][64][40]
        bf16_t (*Bs)[64][40] = (bf16_t(*)[64][40])(smem_raw + 10240);  // [2][64][40]
        const int rem = bid - 4096;
        const int z = rem >> 8, rem2 = rem & 255;
        const float* B = (z == 0) ? Wq : (z == 1) ? Wk : Wv;
        const float* bias = (z == 0) ? bq : (z == 1) ? bk : bv;
        bf16_t* outp = (z == 0) ? Qb : (z == 1) ? Kb : Vb;
        const int m0 = (rem2 >> 4) * 64, n0 = (rem2 & 15) * 64;
        const int lr = t >> 2, lq = t & 3;

        auto stage = [&](bf16_t (*dst)[64][40], const float* __restrict__ Sp, int row0, int buf, int k0) {
            const float* p = Sp + (long)(row0 + lr) * 1024 + k0 + lq * 8;
            float4 u0 = *(const float4*)p;
            float4 u1 = *(const float4*)(p + 4);
            bf16x8 v;
            v[0] = f2b(u0.x); v[1] = f2b(u0.y); v[2] = f2b(u0.z); v[3] = f2b(u0.w);
            v[4] = f2b(u1.x); v[5] = f2b(u1.y); v[6] = f2b(u1.z); v[7] = f2b(u1.w);
            *(bf16x8*)&dst[buf][lr][lq * 8] = v;
        };

        const int wid = t >> 6, lane = t & 63;
        const int wm = (wid >> 1) * 32, wn = (wid & 1) * 32;
        const int ml = lane & 15, kl = (lane >> 4) * 8;
        f32x4 acc[2][2] = {};

        stage(As, x, m0, 0, 0);
        stage(Bs, B, n0, 0, 0);
        __syncthreads();
        for (int kt = 0; kt < 32; kt++) {
            const int buf = kt & 1;
            if (kt + 1 < 32) { stage(As, x, m0, buf ^ 1, (kt + 1) * 32); stage(Bs, B, n0, buf ^ 1, (kt + 1) * 32); }
            bf16x8 a0 = *(const bf16x8*)&As[buf][wm + ml][kl];
            bf16x8 a1 = *(const bf16x8*)&As[buf][wm + 16 + ml][kl];
            bf16x8 b0 = *(const bf16x8*)&Bs[buf][wn + ml][kl];
            bf16x8 b1 = *(const bf16x8*)&Bs[buf][wn + 16 + ml][kl];
            acc[0][0] = __builtin_amdgcn_mfma_f32_16x16x32_bf16(a0, b0, acc[0][0], 0, 0, 0);
            acc[0][1] = __builtin_amdgcn_mfma_f32_16x16x32_bf16(a0, b1, acc[0][1], 0, 0, 0);
            acc[1][0] = __builtin_amdgcn_mfma_f32_16x16x32_bf16(a1, b0, acc[1][0], 0, 0, 0);
            acc[1][1] = __builtin_amdgcn_mfma_f32_16x16x32_bf16(a1, b1, acc[1][1], 0, 0, 0);
            __syncthreads();
        }

#pragma unroll
        for (int mt = 0; mt < 2; mt++)
#pragma unroll
            for (int nt = 0; nt < 2; nt++) {
                f32x4 v = acc[mt][nt];
                const int rbase = m0 + wm + mt * 16 + ((lane >> 4) << 2);
                const int col = n0 + wn + nt * 16 + (lane & 15);
#pragma unroll
                for (int r = 0; r < 4; r++) {
                    const int row = rbase + r;
                    float val = v[r] + bias[col];
                    int h = col >> 6, d = col & 63;
                    if (z < 2) outp[((long)h << 16) + ((long)row << 6) + d] = f2b(val);
                    else       outp[((long)h << 16) + ((long)d << 10) + row] = f2b(val);
                }
            }
    }
}

// ---- final GEMM: out f32 = Yb @ Wy^T + by + x ----
__global__ __launch_bounds__(256) void gemmY_k(const bf16_t* __restrict__ A,
                                               const float* __restrict__ Bw,
                                               const float* __restrict__ bias,
                                               float* __restrict__ outp,
                                               const float* __restrict__ extra) {
    __shared__ bf16_t As[2][64][40];
    __shared__ bf16_t Bs[2][64][40];
    const int t = threadIdx.x;
    const int m0 = blockIdx.y * 64, n0 = blockIdx.x * 64;
    const int lr = t >> 2, lq = t & 3;

    auto stageA = [&](int buf, int k0) {
        const bf16_t* p = A + (long)(m0 + lr) * 1024 + k0 + lq * 8;
        *(bf16x8*)&As[buf][lr][lq * 8] = *(const bf16x8*)p;
    };
    auto stageB = [&](int buf, int k0) {
        const float* p = Bw + (long)(n0 + lr) * 1024 + k0 + lq * 8;
        float4 u0 = *(const float4*)p;
        float4 u1 = *(const float4*)(p + 4);
        bf16x8 v;
        v[0] = f2b(u0.x); v[1] = f2b(u0.y); v[2] = f2b(u0.z); v[3] = f2b(u0.w);
        v[4] = f2b(u1.x); v[5] = f2b(u1.y); v[6] = f2b(u1.z); v[7] = f2b(u1.w);
        *(bf16x8*)&Bs[buf][lr][lq * 8] = v;
    };

    const int wid = t >> 6, lane = t & 63;
    const int wm = (wid >> 1) * 32, wn = (wid & 1) * 32;
    const int ml = lane & 15, kl = (lane >> 4) * 8;
    f32x4 acc[2][2] = {};

    stageA(0, 0);
    stageB(0, 0);
    __syncthreads();
    for (int kt = 0; kt < 32; kt++) {
        const int buf = kt & 1;
        if (kt + 1 < 32) { stageA(buf ^ 1, (kt + 1) * 32); stageB(buf ^ 1, (kt + 1) * 32); }
        bf16x8 a0 = *(const bf16x8*)&As[buf][wm + ml][kl];
        bf16x8 a1 = *(const bf16x8*)&As[buf][wm + 16 + ml][kl];
        bf16x8 b0 = *(const bf16x8*)&Bs[buf][wn + ml][kl];
        bf16x8 b1 = *(const bf16x8*)&Bs[buf][wn + 16 + ml][kl];
        acc[0][0] = __builtin_amdgcn_mfma_f32_16x16x32_bf16(a0, b0, acc[0][0], 0, 0, 0);
        acc[0][1] = __builtin_amdgcn_mfma_f32_16x16x32_bf16(a0, b1, acc[0][1], 0, 0, 0);
        acc[1][0] = __builtin_amdgcn_mfma_f32_16x16x32_bf16(a1, b0, acc[1][0], 0, 0, 0);
        acc[1][1] = __builtin_amdgcn_mfma_f32_16x16x32_bf16(a1, b1, acc[1][1], 0, 0, 0);
        __syncthreads();
    }

#pragma unroll
    for (int mt = 0; mt < 2; mt++)
#pragma unroll
        for (int nt = 0; nt < 2; nt++) {
            f32x4 v = acc[mt][nt];
            const int rbase = m0 + wm + mt * 16 + ((lane >> 4) << 2);
            const int col = n0 + wn + nt * 16 + (lane & 15);
#pragma unroll
            for (int r = 0; r < 4; r++) {
                const int row = rbase + r;
                long idx = ((long)row << 10) + col;
                outp[idx] = v[r] + bias[col] + extra[idx];
            }
        }
}

// ---- fused attention: per (qtile64, head): S=QK^T, p=exp(S)*w, O=pV, O/=sum ----
__global__ __launch_bounds__(256) void attn_kernel(const bf16_t* __restrict__ Q,
                                                   const bf16_t* __restrict__ K,
                                                   const bf16_t* __restrict__ Vt,
                                                   const f16_t* __restrict__ Wf,
                                                   bf16_t* __restrict__ Y) {
    __shared__ bf16_t Qs[64][72];
    __shared__ bf16_t Ks[2][64][72];
    __shared__ bf16_t Vts[2][64][72];
    __shared__ f16_t  Ws[2][64][72];
    __shared__ bf16_t Ps[4][16][72];

    const int qt = blockIdx.x, h = blockIdx.y;
    const int t = threadIdx.x;
    const int w = t >> 6, lane = t & 63;
    const int ml = lane & 15, kq = lane >> 4;
    const int q0 = qt << 6;
    const int sr = t >> 2, sc = (t & 3) << 4;

    const bf16_t* Kh = K + ((long)h << 16);
    const bf16_t* Vh = Vt + ((long)h << 16);
    const f16_t*  Wh = Wf + ((long)h << 20) + ((long)(q0 + sr) << 10);

    {   // stage Q + tile 0
        const bf16_t* src = Q + ((long)h << 16) + ((long)(q0 + sr) << 6) + sc;
        *(bf16x8*)&Qs[sr][sc]     = *(const bf16x8*)src;
        *(bf16x8*)&Qs[sr][sc + 8] = *(const bf16x8*)(src + 8);
        const bf16_t* ks = Kh + ((long)sr << 6) + sc;
        *(bf16x8*)&Ks[0][sr][sc]     = *(const bf16x8*)ks;
        *(bf16x8*)&Ks[0][sr][sc + 8] = *(const bf16x8*)(ks + 8);
        const bf16_t* vs = Vh + ((long)sr << 10) + sc;
        *(bf16x8*)&Vts[0][sr][sc]     = *(const bf16x8*)vs;
        *(bf16x8*)&Vts[0][sr][sc + 8] = *(const bf16x8*)(vs + 8);
        const f16_t* gs = Wh + sc;
        *(f16x8*)&Ws[0][sr][sc]     = *(const f16x8*)gs;
        *(f16x8*)&Ws[0][sr][sc + 8] = *(const f16x8*)(gs + 8);
    }
    __syncthreads();

    const bf16x8 aq0 = *(const bf16x8*)&Qs[(w << 4) + ml][kq * 8];
    const bf16x8 aq1 = *(const bf16x8*)&Qs[(w << 4) + ml][32 + kq * 8];

    f32x4 O[4] = {};
    float lsum[4] = {0.f, 0.f, 0.f, 0.f};

    int buf = 0;
    for (int kt = 0; kt < 16; kt++) {
        bf16x8 rk0, rk1, rv0, rv1;
        f16x8 rw0, rw1;
        const bool pf = (kt < 15);
        if (pf) {  // issue next-tile loads early (T14): latency hides under compute
            const int k0 = (kt + 1) << 6;
            const bf16_t* ks = Kh + ((long)(k0 + sr) << 6) + sc;
            rk0 = *(const bf16x8*)ks; rk1 = *(const bf16x8*)(ks + 8);
            const bf16_t* vs = Vh + ((long)sr << 10) + k0 + sc;
            rv0 = *(const bf16x8*)vs; rv1 = *(const bf16x8*)(vs + 8);
            const f16_t* gs = Wh + k0 + sc;
            rw0 = *(const f16x8*)gs; rw1 = *(const f16x8*)(gs + 8);
        }

        // QK^T: wave tile = 16 q-rows x 64 keys
        f32x4 s[4] = {};
#pragma unroll
        for (int c = 0; c < 4; c++) {
            bf16x8 bk0 = *(const bf16x8*)&Ks[buf][(c << 4) + ml][kq * 8];
            bf16x8 bk1 = *(const bf16x8*)&Ks[buf][(c << 4) + ml][32 + kq * 8];
            s[c] = __builtin_amdgcn_mfma_f32_16x16x32_bf16(aq0, bk0, s[c], 0, 0, 0);
            s[c] = __builtin_amdgcn_mfma_f32_16x16x32_bf16(aq1, bk1, s[c], 0, 0, 0);
        }
        // p = exp(s) * w   (softmax(qk+log w) == w*e^qk/sum; no max needed: |s|<~50)
#pragma unroll
        for (int c = 0; c < 4; c++) {
#pragma unroll
            for (int r = 0; r < 4; r++) {
                float wv = (float)Ws[buf][(w << 4) + (kq << 2) + r][(c << 4) + ml];
                float p = __expf(s[c][r]) * wv;
                lsum[r] += p;
                Ps[w][(kq << 2) + r][(c << 4) + ml] = f2b(p);
            }
        }
        // PV: A = P (per-wave LDS transpose), B = Vt rows (dv)
        const bf16x8 pa0 = *(const bf16x8*)&Ps[w][ml][kq * 8];
        const bf16x8 pa1 = *(const bf16x8*)&Ps[w][ml][32 + kq * 8];
#pragma unroll
        for (int c = 0; c < 4; c++) {
            bf16x8 v0 = *(const bf16x8*)&Vts[buf][(c << 4) + ml][kq * 8];
            bf16x8 v1 = *(const bf16x8*)&Vts[buf][(c << 4) + ml][32 + kq * 8];
            O[c] = __builtin_amdgcn_mfma_f32_16x16x32_bf16(pa0, v0, O[c], 0, 0, 0);
            O[c] = __builtin_amdgcn_mfma_f32_16x16x32_bf16(pa1, v1, O[c], 0, 0, 0);
        }

        if (pf) {  // write-late staging into the other buffer
            const int nb = buf ^ 1;
            *(bf16x8*)&Ks[nb][sr][sc]      = rk0;
            *(bf16x8*)&Ks[nb][sr][sc + 8]  = rk1;
            *(bf16x8*)&Vts[nb][sr][sc]     = rv0;
            *(bf16x8*)&Vts[nb][sr][sc + 8] = rv1;
            *(f16x8*)&Ws[nb][sr][sc]       = rw0;
            *(f16x8*)&Ws[nb][sr][sc + 8]   = rw1;
        }
        __syncthreads();
        buf ^= 1;
    }

#pragma unroll
    for (int r = 0; r < 4; r++) {
        float v = lsum[r];
        v += __shfl_xor(v, 1); v += __shfl_xor(v, 2);
        v += __shfl_xor(v, 4); v += __shfl_xor(v, 8);
        lsum[r] = 1.0f / v;
    }
    const int rowb = q0 + (w << 4) + (kq << 2);
    const int colb = (h << 6) + ml;
#pragma unroll
    for (int c = 0; c < 4; c++)
#pragma unroll
        for (int r = 0; r < 4; r++)
            Y[((long)(rowb + r) << 10) + colb + (c << 4)] = f2b(O[c][r] * lsum[r]);
}

extern "C" void kernel_launch(void* const* d_in, const int* in_sizes, int n_in,
                              void* d_out, int out_size, void* d_ws, size_t ws_size,
                              hipStream_t stream) {
    const float* x  = (const float*)d_in[0];
    const float* pe = (const float*)d_in[1];
    const float* Wq = (const float*)d_in[2];
    const float* bq = (const float*)d_in[3];
    const float* Wk = (const float*)d_in[4];
    const float* bk = (const float*)d_in[5];
    const float* Wv = (const float*)d_in[6];
    const float* bv = (const float*)d_in[7];
    const float* Wg = (const float*)d_in[8];
    const float* bg = (const float*)d_in[9];
    const float* Wy = (const float*)d_in[10];
    const float* by = (const float*)d_in[11];

    char* ws = (char*)d_ws;
    f16_t*  Wf = (f16_t*)ws;                         // 32 MB
    bf16_t* Qb = (bf16_t*)(ws + (32ul << 20));       // 2 MB
    bf16_t* Kb = (bf16_t*)(ws + (34ul << 20));       // 2 MB
    bf16_t* Vb = (bf16_t*)(ws + (36ul << 20));       // 2 MB
    bf16_t* Yb = (bf16_t*)(ws + (38ul << 20));       // 2 MB

    fused_g_proj_k<<<4096 + 768, 256, 0, stream>>>(pe, Wg, bg, Wf,
                                                   x, Wq, bq, Qb, Wk, bk, Kb, Wv, bv, Vb);
    attn_kernel<<<dim3(16, 16), 256, 0, stream>>>(Qb, Kb, Vb, Wf, Yb);
    gemmY_k<<<dim3(16, 16), 256, 0, stream>>>(Yb, Wy, by, (float*)d_out, x);
}

// Round 14
// 121.135 us; speedup vs baseline: 2.0919x; 1.8869x over previous
//
#include <hip/hip_runtime.h>
#include <hip/hip_bf16.h>

// N=1024 rois, DF=1024, DK=DV=DG=64, NR=16 heads.
// ws: [0,32MB) w=max(relu(pe@Wg^T+bg),1e-6) f16 [16][1024][1024]
//     [32MB) Q bf16 [16][1024][64]; [34MB) K same; [36MB) Vt bf16 [16][64][1024]; [38MB) Y bf16 [1024][1024]

typedef __bf16 bf16_t;
typedef _Float16 f16_t;
typedef __attribute__((ext_vector_type(8))) __bf16 bf16x8;
typedef __attribute__((ext_vector_type(8))) _Float16 f16x8;
typedef __attribute__((ext_vector_type(4))) float f32x4;

__device__ inline bf16_t f2b(float f) {
    unsigned u = __builtin_bit_cast(unsigned, f);
    unsigned r = u + 0x7fffu + ((u >> 16) & 1u);
    unsigned short h = (unsigned short)(r >> 16);
    return __builtin_bit_cast(bf16_t, h);
}

// ---- fused (g + Q/K/V projections) heterogeneous kernel ----
// blocks [0,768): proj z=bid/256 (0:Q,1:K,2:V), 16x16 tile grid
// blocks [768,768+16384): g (R6-proven body).
// R13 lesson (Little's law): the fused kernel previously declared g-tile(16KB)
// AND proj buffers(20KB) = 36KB/block -> 4 blocks/CU -> intake ~26B/cyc/CU
// ~= the observed 2.5-2.8 TB/s ceiling. UNION the LDS (20KB) -> 8 blocks/CU.
__global__ __launch_bounds__(256) void fused_g_proj_k(
        const float* __restrict__ pe, const float* __restrict__ Wg, const float* __restrict__ bg,
        f16_t* __restrict__ Wout,
        const float* __restrict__ x,
        const float* __restrict__ Wq, const float* __restrict__ bq, bf16_t* __restrict__ Qb,
        const float* __restrict__ Wk, const float* __restrict__ bk, bf16_t* __restrict__ Kb,
        const float* __restrict__ Wv, const float* __restrict__ bv, bf16_t* __restrict__ Vb) {
    __shared__ char smem_raw[20480];   // union: proj As|Bs (10240+10240) / g tile4 (16384)
    const int bid = blockIdx.x;
    const int t = threadIdx.x;

    if (bid < 768) {
        // ================= projection GEMM: C = x @ W^T + b =================
        bf16_t (*As)[64][40] = (bf16_t(*)[64][40])smem_raw;            // [2][64][40]
        bf16_t (*Bs)[64][40] = (bf16_t(*)[64][40])(smem_raw + 10240);  // [2][64][40]
        const int z = bid >> 8, rem = bid & 255;
        const float* B = (z == 0) ? Wq : (z == 1) ? Wk : Wv;
        const float* bias = (z == 0) ? bq : (z == 1) ? bk : bv;
        bf16_t* outp = (z == 0) ? Qb : (z == 1) ? Kb : Vb;
        const int m0 = (rem >> 4) * 64, n0 = (rem & 15) * 64;
        const int lr = t >> 2, lq = t & 3;

        auto stage = [&](bf16_t (*dst)[64][40], const float* __restrict__ Sp, int row0, int buf, int k0) {
            const float* p = Sp + (long)(row0 + lr) * 1024 + k0 + lq * 8;
            float4 u0 = *(const float4*)p;
            float4 u1 = *(const float4*)(p + 4);
            bf16x8 v;
            v[0] = f2b(u0.x); v[1] = f2b(u0.y); v[2] = f2b(u0.z); v[3] = f2b(u0.w);
            v[4] = f2b(u1.x); v[5] = f2b(u1.y); v[6] = f2b(u1.z); v[7] = f2b(u1.w);
            *(bf16x8*)&dst[buf][lr][lq * 8] = v;
        };

        const int wid = t >> 6, lane = t & 63;
        const int wm = (wid >> 1) * 32, wn = (wid & 1) * 32;
        const int ml = lane & 15, kl = (lane >> 4) * 8;
        f32x4 acc[2][2] = {};

        stage(As, x, m0, 0, 0);
        stage(Bs, B, n0, 0, 0);
        __syncthreads();
        for (int kt = 0; kt < 32; kt++) {
            const int buf = kt & 1;
            if (kt + 1 < 32) { stage(As, x, m0, buf ^ 1, (kt + 1) * 32); stage(Bs, B, n0, buf ^ 1, (kt + 1) * 32); }
            bf16x8 a0 = *(const bf16x8*)&As[buf][wm + ml][kl];
            bf16x8 a1 = *(const bf16x8*)&As[buf][wm + 16 + ml][kl];
            bf16x8 b0 = *(const bf16x8*)&Bs[buf][wn + ml][kl];
            bf16x8 b1 = *(const bf16x8*)&Bs[buf][wn + 16 + ml][kl];
            acc[0][0] = __builtin_amdgcn_mfma_f32_16x16x32_bf16(a0, b0, acc[0][0], 0, 0, 0);
            acc[0][1] = __builtin_amdgcn_mfma_f32_16x16x32_bf16(a0, b1, acc[0][1], 0, 0, 0);
            acc[1][0] = __builtin_amdgcn_mfma_f32_16x16x32_bf16(a1, b0, acc[1][0], 0, 0, 0);
            acc[1][1] = __builtin_amdgcn_mfma_f32_16x16x32_bf16(a1, b1, acc[1][1], 0, 0, 0);
            __syncthreads();
        }

#pragma unroll
        for (int mt = 0; mt < 2; mt++)
#pragma unroll
            for (int nt = 0; nt < 2; nt++) {
                f32x4 v = acc[mt][nt];
                const int rbase = m0 + wm + mt * 16 + ((lane >> 4) << 2);
                const int col = n0 + wn + nt * 16 + (lane & 15);
#pragma unroll
                for (int r = 0; r < 4; r++) {
                    const int row = rbase + r;
                    float val = v[r] + bias[col];
                    int h = col >> 6, d = col & 63;
                    if (z < 2) outp[((long)h << 16) + ((long)row << 6) + d] = f2b(val);
                    else       outp[((long)h << 16) + ((long)d << 10) + row] = f2b(val);
                }
            }
    } else {
        // ================= g: w = max(relu(pe@Wg^T+bg), 1e-6) =================
        // f32 math (precision cliff at relu boundary — round-2 lesson).
        float4 (*tile4)[16] = (float4(*)[16])smem_raw;   // [64][16], XOR-swizzled
        const long rowbase = (long)(bid - 768) * 64;     // flat pair index = i*1024 + j
        const float4* src = (const float4*)(pe + rowbase * 64);
#pragma unroll
        for (int p = 0; p < 4; p++) {
            float4 v = src[p * 256 + t];
            int fi = p * 256 + t;            // float4 index: row = fi>>4, chunk = fi&15
            int r = fi >> 4, c = fi & 15;
            tile4[r][c ^ (r & 15)] = v;      // XOR swizzle: conflict-free b128 r/w
        }
        __syncthreads();
        const int r = t & 63;
        const int hbu = __builtin_amdgcn_readfirstlane((t >> 6) << 2);  // wave-uniform head base
        const float* wg0 = Wg + hbu * 64;
        const float* wg1 = wg0 + 64;
        const float* wg2 = wg0 + 128;
        const float* wg3 = wg0 + 192;
        float a0 = bg[hbu + 0], a1 = bg[hbu + 1], a2 = bg[hbu + 2], a3 = bg[hbu + 3];
#pragma unroll
        for (int dq = 0; dq < 16; dq++) {
            float4 pv = tile4[r][dq ^ (r & 15)];
            float4 w0 = *(const float4*)(wg0 + dq * 4);
            float4 w1 = *(const float4*)(wg1 + dq * 4);
            float4 w2 = *(const float4*)(wg2 + dq * 4);
            float4 w3 = *(const float4*)(wg3 + dq * 4);
            a0 += pv.x * w0.x + pv.y * w0.y + pv.z * w0.z + pv.w * w0.w;
            a1 += pv.x * w1.x + pv.y * w1.y + pv.z * w1.z + pv.w * w1.w;
            a2 += pv.x * w2.x + pv.y * w2.y + pv.z * w2.z + pv.w * w2.w;
            a3 += pv.x * w3.x + pv.y * w3.y + pv.z * w3.z + pv.w * w3.w;
        }
        // w = max(relu(a), 1e-6) == max(a, 1e-6); softmax(qk+log w) == w*e^qk/sum
        // stores: 64 lanes -> 128B contiguous line per head (R9 lesson)
        Wout[(long)(hbu + 0) * 1048576 + rowbase + r] = (f16_t)fmaxf(a0, 1e-6f);
        Wout[(long)(hbu + 1) * 1048576 + rowbase + r] = (f16_t)fmaxf(a1, 1e-6f);
        Wout[(long)(hbu + 2) * 1048576 + rowbase + r] = (f16_t)fmaxf(a2, 1e-6f);
        Wout[(long)(hbu + 3) * 1048576 + rowbase + r] = (f16_t)fmaxf(a3, 1e-6f);
    }
}

// ---- final GEMM: out f32 = Yb @ Wy^T + by + x ----
__global__ __launch_bounds__(256) void gemmY_k(const bf16_t* __restrict__ A,
                                               const float* __restrict__ Bw,
                                               const float* __restrict__ bias,
                                               float* __restrict__ outp,
                                               const float* __restrict__ extra) {
    __shared__ bf16_t As[2][64][40];
    __shared__ bf16_t Bs[2][64][40];
    const int t = threadIdx.x;
    const int m0 = blockIdx.y * 64, n0 = blockIdx.x * 64;
    const int lr = t >> 2, lq = t & 3;

    auto stageA = [&](int buf, int k0) {
        const bf16_t* p = A + (long)(m0 + lr) * 1024 + k0 + lq * 8;
        *(bf16x8*)&As[buf][lr][lq * 8] = *(const bf16x8*)p;
    };
    auto stageB = [&](int buf, int k0) {
        const float* p = Bw + (long)(n0 + lr) * 1024 + k0 + lq * 8;
        float4 u0 = *(const float4*)p;
        float4 u1 = *(const float4*)(p + 4);
        bf16x8 v;
        v[0] = f2b(u0.x); v[1] = f2b(u0.y); v[2] = f2b(u0.z); v[3] = f2b(u0.w);
        v[4] = f2b(u1.x); v[5] = f2b(u1.y); v[6] = f2b(u1.z); v[7] = f2b(u1.w);
        *(bf16x8*)&Bs[buf][lr][lq * 8] = v;
    };

    const int wid = t >> 6, lane = t & 63;
    const int wm = (wid >> 1) * 32, wn = (wid & 1) * 32;
    const int ml = lane & 15, kl = (lane >> 4) * 8;
    f32x4 acc[2][2] = {};

    stageA(0, 0);
    stageB(0, 0);
    __syncthreads();
    for (int kt = 0; kt < 32; kt++) {
        const int buf = kt & 1;
        if (kt + 1 < 32) { stageA(buf ^ 1, (kt + 1) * 32); stageB(buf ^ 1, (kt + 1) * 32); }
        bf16x8 a0 = *(const bf16x8*)&As[buf][wm + ml][kl];
        bf16x8 a1 = *(const bf16x8*)&As[buf][wm + 16 + ml][kl];
        bf16x8 b0 = *(const bf16x8*)&Bs[buf][wn + ml][kl];
        bf16x8 b1 = *(const bf16x8*)&Bs[buf][wn + 16 + ml][kl];
        acc[0][0] = __builtin_amdgcn_mfma_f32_16x16x32_bf16(a0, b0, acc[0][0], 0, 0, 0);
        acc[0][1] = __builtin_amdgcn_mfma_f32_16x16x32_bf16(a0, b1, acc[0][1], 0, 0, 0);
        acc[1][0] = __builtin_amdgcn_mfma_f32_16x16x32_bf16(a1, b0, acc[1][0], 0, 0, 0);
        acc[1][1] = __builtin_amdgcn_mfma_f32_16x16x32_bf16(a1, b1, acc[1][1], 0, 0, 0);
        __syncthreads();
    }

#pragma unroll
    for (int mt = 0; mt < 2; mt++)
#pragma unroll
        for (int nt = 0; nt < 2; nt++) {
            f32x4 v = acc[mt][nt];
            const int rbase = m0 + wm + mt * 16 + ((lane >> 4) << 2);
            const int col = n0 + wn + nt * 16 + (lane & 15);
#pragma unroll
            for (int r = 0; r < 4; r++) {
                const int row = rbase + r;
                long idx = ((long)row << 10) + col;
                outp[idx] = v[r] + bias[col] + extra[idx];
            }
        }
}

// ---- fused attention: per (qtile64, head): S=QK^T, p=exp(S)*w, O=pV, O/=sum ----
__global__ __launch_bounds__(256) void attn_kernel(const bf16_t* __restrict__ Q,
                                                   const bf16_t* __restrict__ K,
                                                   const bf16_t* __restrict__ Vt,
                                                   const f16_t* __restrict__ Wf,
                                                   bf16_t* __restrict__ Y) {
    __shared__ bf16_t Qs[64][72];
    __shared__ bf16_t Ks[2][64][72];
    __shared__ bf16_t Vts[2][64][72];
    __shared__ f16_t  Ws[2][64][72];
    __shared__ bf16_t Ps[4][16][72];

    const int qt = blockIdx.x, h = blockIdx.y;
    const int t = threadIdx.x;
    const int w = t >> 6, lane = t & 63;
    const int ml = lane & 15, kq = lane >> 4;
    const int q0 = qt << 6;
    const int sr = t >> 2, sc = (t & 3) << 4;

    const bf16_t* Kh = K + ((long)h << 16);
    const bf16_t* Vh = Vt + ((long)h << 16);
    const f16_t*  Wh = Wf + ((long)h << 20) + ((long)(q0 + sr) << 10);

    {   // stage Q + tile 0
        const bf16_t* src = Q + ((long)h << 16) + ((long)(q0 + sr) << 6) + sc;
        *(bf16x8*)&Qs[sr][sc]     = *(const bf16x8*)src;
        *(bf16x8*)&Qs[sr][sc + 8] = *(const bf16x8*)(src + 8);
        const bf16_t* ks = Kh + ((long)sr << 6) + sc;
        *(bf16x8*)&Ks[0][sr][sc]     = *(const bf16x8*)ks;
        *(bf16x8*)&Ks[0][sr][sc + 8] = *(const bf16x8*)(ks + 8);
        const bf16_t* vs = Vh + ((long)sr << 10) + sc;
        *(bf16x8*)&Vts[0][sr][sc]     = *(const bf16x8*)vs;
        *(bf16x8*)&Vts[0][sr][sc + 8] = *(const bf16x8*)(vs + 8);
        const f16_t* gs = Wh + sc;
        *(f16x8*)&Ws[0][sr][sc]     = *(const f16x8*)gs;
        *(f16x8*)&Ws[0][sr][sc + 8] = *(const f16x8*)(gs + 8);
    }
    __syncthreads();

    const bf16x8 aq0 = *(const bf16x8*)&Qs[(w << 4) + ml][kq * 8];
    const bf16x8 aq1 = *(const bf16x8*)&Qs[(w << 4) + ml][32 + kq * 8];

    f32x4 O[4] = {};
    float lsum[4] = {0.f, 0.f, 0.f, 0.f};

    int buf = 0;
    for (int kt = 0; kt < 16; kt++) {
        bf16x8 rk0, rk1, rv0, rv1;
        f16x8 rw0, rw1;
        const bool pf = (kt < 15);
        if (pf) {  // issue next-tile loads early (T14): latency hides under compute
            const int k0 = (kt + 1) << 6;
            const bf16_t* ks = Kh + ((long)(k0 + sr) << 6) + sc;
            rk0 = *(const bf16x8*)ks; rk1 = *(const bf16x8*)(ks + 8);
            const bf16_t* vs = Vh + ((long)sr << 10) + k0 + sc;
            rv0 = *(const bf16x8*)vs; rv1 = *(const bf16x8*)(vs + 8);
            const f16_t* gs = Wh + k0 + sc;
            rw0 = *(const f16x8*)gs; rw1 = *(const f16x8*)(gs + 8);
        }

        // QK^T: wave tile = 16 q-rows x 64 keys
        f32x4 s[4] = {};
#pragma unroll
        for (int c = 0; c < 4; c++) {
            bf16x8 bk0 = *(const bf16x8*)&Ks[buf][(c << 4) + ml][kq * 8];
            bf16x8 bk1 = *(const bf16x8*)&Ks[buf][(c << 4) + ml][32 + kq * 8];
            s[c] = __builtin_amdgcn_mfma_f32_16x16x32_bf16(aq0, bk0, s[c], 0, 0, 0);
            s[c] = __builtin_amdgcn_mfma_f32_16x16x32_bf16(aq1, bk1, s[c], 0, 0, 0);
        }
        // p = exp(s) * w   (softmax(qk+log w) == w*e^qk/sum; no max needed: |s|<~50)
#pragma unroll
        for (int c = 0; c < 4; c++) {
#pragma unroll
            for (int r = 0; r < 4; r++) {
                float wv = (float)Ws[buf][(w << 4) + (kq << 2) + r][(c << 4) + ml];
                float p = __expf(s[c][r]) * wv;
                lsum[r] += p;
                Ps[w][(kq << 2) + r][(c << 4) + ml] = f2b(p);
            }
        }
        // PV: A = P (per-wave LDS transpose), B = Vt rows (dv)
        const bf16x8 pa0 = *(const bf16x8*)&Ps[w][ml][kq * 8];
        const bf16x8 pa1 = *(const bf16x8*)&Ps[w][ml][32 + kq * 8];
#pragma unroll
        for (int c = 0; c < 4; c++) {
            bf16x8 v0 = *(const bf16x8*)&Vts[buf][(c << 4) + ml][kq * 8];
            bf16x8 v1 = *(const bf16x8*)&Vts[buf][(c << 4) + ml][32 + kq * 8];
            O[c] = __builtin_amdgcn_mfma_f32_16x16x32_bf16(pa0, v0, O[c], 0, 0, 0);
            O[c] = __builtin_amdgcn_mfma_f32_16x16x32_bf16(pa1, v1, O[c], 0, 0, 0);
        }

        if (pf) {  // write-late staging into the other buffer
            const int nb = buf ^ 1;
            *(bf16x8*)&Ks[nb][sr][sc]      = rk0;
            *(bf16x8*)&Ks[nb][sr][sc + 8]  = rk1;
            *(bf16x8*)&Vts[nb][sr][sc]     = rv0;
            *(bf16x8*)&Vts[nb][sr][sc + 8] = rv1;
            *(f16x8*)&Ws[nb][sr][sc]       = rw0;
            *(f16x8*)&Ws[nb][sr][sc + 8]   = rw1;
        }
        __syncthreads();
        buf ^= 1;
    }

#pragma unroll
    for (int r = 0; r < 4; r++) {
        float v = lsum[r];
        v += __shfl_xor(v, 1); v += __shfl_xor(v, 2);
        v += __shfl_xor(v, 4); v += __shfl_xor(v, 8);
        lsum[r] = 1.0f / v;
    }
    const int rowb = q0 + (w << 4) + (kq << 2);
    const int colb = (h << 6) + ml;
#pragma unroll
    for (int c = 0; c < 4; c++)
#pragma unroll
        for (int r = 0; r < 4; r++)
            Y[((long)(rowb + r) << 10) + colb + (c << 4)] = f2b(O[c][r] * lsum[r]);
}

extern "C" void kernel_launch(void* const* d_in, const int* in_sizes, int n_in,
                              void* d_out, int out_size, void* d_ws, size_t ws_size,
                              hipStream_t stream) {
    const float* x  = (const float*)d_in[0];
    const float* pe = (const float*)d_in[1];
    const float* Wq = (const float*)d_in[2];
    const float* bq = (const float*)d_in[3];
    const float* Wk = (const float*)d_in[4];
    const float* bk = (const float*)d_in[5];
    const float* Wv = (const float*)d_in[6];
    const float* bv = (const float*)d_in[7];
    const float* Wg = (const float*)d_in[8];
    const float* bg = (const float*)d_in[9];
    const float* Wy = (const float*)d_in[10];
    const float* by = (const float*)d_in[11];

    char* ws = (char*)d_ws;
    f16_t*  Wf = (f16_t*)ws;                         // 32 MB
    bf16_t* Qb = (bf16_t*)(ws + (32ul << 20));       // 2 MB
    bf16_t* Kb = (bf16_t*)(ws + (34ul << 20));       // 2 MB
    bf16_t* Vb = (bf16_t*)(ws + (36ul << 20));       // 2 MB
    bf16_t* Yb = (bf16_t*)(ws + (38ul << 20));       // 2 MB

    fused_g_proj_k<<<768 + 16384, 256, 0, stream>>>(pe, Wg, bg, Wf,
                                                    x, Wq, bq, Qb, Wk, bk, Kb, Wv, bv, Vb);
    attn_kernel<<<dim3(16, 16), 256, 0, stream>>>(Qb, Kb, Vb, Wf, Yb);
    gemmY_k<<<dim3(16, 16), 256, 0, stream>>>(Yb, Wy, by, (float*)d_out, x);
}